// Round 15
// baseline (6412.466 us; speedup 1.0000x reference)
//
#include <hip/hip_runtime.h>
#include <hip/hip_bf16.h>

#define B 64
#define SEQ 256
#define IN 512
#define HD 1024
#define ODIM 512
#define WGTH 512

typedef __attribute__((ext_vector_type(8))) short bf16x8;
typedef __attribute__((ext_vector_type(4))) float f32x4;
typedef __attribute__((ext_vector_type(4))) unsigned short u16x4;
typedef __attribute__((ext_vector_type(4))) unsigned int u32x4;

__device__ __forceinline__ f32x4 mfma16(bf16x8 a, bf16x8 b, f32x4 c) {
  return __builtin_amdgcn_mfma_f32_16x16x32_bf16(a, b, c, 0, 0, 0);
}

__device__ __forceinline__ unsigned short f2bf(float f) {
  unsigned u = __builtin_bit_cast(unsigned, f);
  u += 0x7FFFu + ((u >> 16) & 1u);
  return (unsigned short)(u >> 16);
}

__device__ __forceinline__ float sigmoidf_(float x) { return 1.f / (1.f + expf(-x)); }

// coalesced 16B write-through store (LLC-coherent cross-XCD) — R12 proven
__device__ __forceinline__ void stc16(unsigned short* p, bf16x8 v) {
  asm volatile("global_store_dwordx4 %0, %1, off sc1" : : "v"(p), "v"(v) : "memory");
}

// coherent 16B load: bypass L1+L2, read LLC. No waitcnt — caller manages vmcnt.
__device__ __forceinline__ void ldg16(bf16x8& d, const unsigned short* p) {
  asm volatile("global_load_dwordx4 %0, %1, off sc0 sc1" : "=v"(d) : "v"(p) : "memory");
}

template <int N>
__device__ __forceinline__ void vmwait() {
  asm volatile("s_waitcnt vmcnt(%0)" :: "i"(N) : "memory");
  __builtin_amdgcn_sched_barrier(0);
}

__device__ __forceinline__ bf16x8 sent8() {
  bf16x8 v;
  #pragma unroll
  for (int i = 0; i < 8; ++i) v[i] = (short)0x7FC0;
  return v;
}

// any halfword == 0x7FC0 (sentinel NaN) in a 16B chunk?
__device__ __forceinline__ unsigned badchk(bf16x8 v) {
  u32x4 u = __builtin_bit_cast(u32x4, v);
  unsigned b = 0;
  #pragma unroll
  for (int i = 0; i < 4; ++i) {
    unsigned x = u[i] ^ 0x7FC07FC0u;
    b |= (x - 0x00010001u) & ~x & 0x80008000u;
  }
  return b;
}

// ---------------- flags (lagged WAR / skew-bound only) ----------------
__device__ __forceinline__ void flag_set(unsigned* fl, int wgl, unsigned val) {
  if (threadIdx.x == 0) {
    unsigned* p = fl + wgl * 16;
    asm volatile("s_waitcnt vmcnt(0)\n\t"
                 "global_store_dword %0, %1, off sc0 sc1"
                 :: "v"(p), "v"(val) : "memory");
  }
}

__device__ __forceinline__ void flag_poll(const unsigned* fl, unsigned tgt) {
  if (threadIdx.x < 64) {
    const unsigned* p = fl + threadIdx.x * 16;
    for (;;) {
      unsigned v;
      asm volatile("global_load_dword %0, %1, off sc0 sc1\n\t"
                   "s_waitcnt vmcnt(0)" : "=v"(v) : "v"(p) : "memory");
      if (__ballot(v < tgt) == 0ull) break;
      __builtin_amdgcn_s_sleep(2);
    }
  }
  __syncthreads();
}

// ---- x: f32 -> bf16 ----
__global__ void f32_to_bf16_k(const float* __restrict__ s, unsigned short* __restrict__ d, int n) {
  int i = (blockIdx.x * blockDim.x + threadIdx.x) * 4;
  if (i < n) {
    float4 v = *reinterpret_cast<const float4*>(s + i);
    u16x4 o;
    o.x = f2bf(v.x); o.y = f2bf(v.y); o.z = f2bf(v.z); o.w = f2bf(v.w);
    *reinterpret_cast<u16x4*>(d + i) = o;
  }
}

// ---- sentinel fill ----
__global__ void fill_sent(unsigned* __restrict__ d, size_t n) {
  size_t i = (size_t)blockIdx.x * blockDim.x + threadIdx.x;
  size_t st = (size_t)gridDim.x * blockDim.x;
  for (; i < n; i += st) d[i] = 0x7FC07FC0u;
}

// ---- weights: f32 [N][K] -> bf16 packed MFMA B-fragment layout ----
struct PackSeg { const float* s; unsigned short* d; int N; int K; };
struct PackP { PackSeg seg[13]; };

__global__ void pack_w(PackP P) {
  PackSeg sg = P.seg[blockIdx.y];
  const int kc_n = sg.K >> 5;
  const int total = (sg.N * sg.K) >> 3;
  for (int i = blockIdx.x * blockDim.x + threadIdx.x; i < total; i += gridDim.x * blockDim.x) {
    int lane = i & 63;
    int block = i >> 6;
    int kc = block % kc_n;
    int nt = block / kc_n;
    int n = nt * 16 + (lane & 15);
    int k = kc * 32 + (lane >> 4) * 8;
    const float* s = sg.s + (size_t)n * sg.K + k;
    float4 v0 = *(const float4*)(s);
    float4 v1 = *(const float4*)(s + 4);
    u16x4 o0, o1;
    o0.x = f2bf(v0.x); o0.y = f2bf(v0.y); o0.z = f2bf(v0.z); o0.w = f2bf(v0.w);
    o1.x = f2bf(v1.x); o1.y = f2bf(v1.y); o1.z = f2bf(v1.z); o1.w = f2bf(v1.w);
    unsigned short* dp = sg.d + (size_t)i * 8;
    *(u16x4*)(dp) = o0;
    *(u16x4*)(dp + 4) = o1;
  }
}

struct GruP {
  const unsigned short* xbf;
  const unsigned short* wx[2][3];
  const unsigned short* wh[2][3];
  const float* bx[2][3];
  unsigned short* h0r;     // ring 8 x [B][HD]
  unsigned short* h1r;     // ring 4
  unsigned short* rhr[2];  // ring 4 per layer
  unsigned short* y1;
  float* outh;
  unsigned* bar;           // 4 flag regions x 4KB (L0A,L0B,L1A,L1B)
};

#define GISS(mt, sArr, baseP) do { \
    const unsigned short* _p = (baseP) + (size_t)(16 * (mt) + lo) * HD; \
    ldg16(sArr[0], _p);      ldg16(sArr[1], _p + 32); \
    ldg16(sArr[2], _p + 64); ldg16(sArr[3], _p + 96); \
  } while (0)

// per-wave sentinel poll: load own 16 chunks, retry until no sentinel
#define SPOLL(baseP) do { \
    for (;;) { \
      GISS(0, s0, baseP); GISS(1, s1, baseP); GISS(2, s2, baseP); GISS(3, s3, baseP); \
      vmwait<0>(); \
      unsigned _bad = badchk(s0[0]) | badchk(s0[1]) | badchk(s0[2]) | badchk(s0[3]) \
                    | badchk(s1[0]) | badchk(s1[1]) | badchk(s1[2]) | badchk(s1[3]) \
                    | badchk(s2[0]) | badchk(s2[1]) | badchk(s2[2]) | badchk(s2[3]) \
                    | badchk(s3[0]) | badchk(s3[1]) | badchk(s3[2]) | badchk(s3[3]); \
      if (__ballot(_bad != 0) == 0ull) break; \
      __builtin_amdgcn_s_sleep(1); \
    } \
  } while (0)

#define GCMP2(mt, sArr, wz_, wr_) do { \
    f32x4 _a = vz[mt], _b = vr[mt]; \
    _a = mfma16(sArr[0], wz_[0], _a); _b = mfma16(sArr[0], wr_[0], _b); \
    _a = mfma16(sArr[1], wz_[1], _a); _b = mfma16(sArr[1], wr_[1], _b); \
    _a = mfma16(sArr[2], wz_[2], _a); _b = mfma16(sArr[2], wr_[2], _b); \
    _a = mfma16(sArr[3], wz_[3], _a); _b = mfma16(sArr[3], wr_[3], _b); \
    vz[mt] = _a; vr[mt] = _b; \
  } while (0)

#define YCMP3(mt, s) do { \
    f32x4 _z = vz[mt], _r = vr[mt], _g = vg[mt]; \
    _z = mfma16(s[0], wxz[0], _z); _r = mfma16(s[0], wxr[0], _r); _g = mfma16(s[0], wxg[0], _g); \
    _z = mfma16(s[1], wxz[1], _z); _r = mfma16(s[1], wxr[1], _r); _g = mfma16(s[1], wxg[1], _g); \
    _z = mfma16(s[2], wxz[2], _z); _r = mfma16(s[2], wxr[2], _r); _g = mfma16(s[2], wxg[2], _g); \
    _z = mfma16(s[3], wxz[3], _z); _r = mfma16(s[3], wxr[3], _r); _g = mfma16(s[3], wxg[3], _g); \
    vz[mt] = _z; vr[mt] = _r; vg[mt] = _g; \
  } while (0)

#define RCMP1(mt, s) do { \
    f32x4 _a = vg[mt]; \
    _a = mfma16(s[0], whg[0], _a); _a = mfma16(s[1], whg[1], _a); \
    _a = mfma16(s[2], whg[2], _a); _a = mfma16(s[3], whg[3], _a); \
    vg[mt] = _a; \
  } while (0)

template <int LAYER>
__device__ void gru_body(const GruP& P, f32x4 (*red)[7][64]) {
  const int wgl = (int)blockIdx.x & 63;
  const int tid = threadIdx.x;
  const int w = tid >> 6;            // 8 waves: k-slice owner; waves 0-3 own m-tile w
  const int lane = tid & 63;
  const int lo = lane & 15, hi = lane >> 4;
  const int cC = wgl * 16 + lo;
  constexpr int KX = LAYER ? HD : IN;
  constexpr int CX = KX / 256;       // L0:2, L1:4
  constexpr int CH = 4;
  const int kslH = w * 128 + hi * 8;
  const int kslX = w * (KX >> 3) + hi * 8;
  const size_t SLOT = (size_t)B * HD;

  // register-resident weights (packed frag layout, ntile = wgl)
  bf16x8 whz[CH], whr[CH], whg[CH], wxz[CX], wxr[CX], wxg[CX];
  #pragma unroll
  for (int c = 0; c < CH; ++c) {
    size_t o = ((size_t)wgl * (HD / 32) + w * CH + c) * 512 + (size_t)lane * 8;
    whz[c] = *(const bf16x8*)(P.wh[LAYER][0] + o);
    whr[c] = *(const bf16x8*)(P.wh[LAYER][1] + o);
    whg[c] = *(const bf16x8*)(P.wh[LAYER][2] + o);
  }
  #pragma unroll
  for (int c = 0; c < CX; ++c) {
    size_t o = ((size_t)wgl * (KX / 32) + w * CX + c) * 512 + (size_t)lane * 8;
    wxz[c] = *(const bf16x8*)(P.wx[LAYER][0] + o);
    wxr[c] = *(const bf16x8*)(P.wx[LAYER][1] + o);
    wxg[c] = *(const bf16x8*)(P.wx[LAYER][2] + o);
  }
  const float bz = P.bx[LAYER][0][cC];
  const float br = P.bx[LAYER][1][cC];
  const float bg = P.bx[LAYER][2][cC];
  unsigned short* RHr = P.rhr[LAYER];

  unsigned* flAmy = P.bar + (LAYER * 2 + 0) * 1024;
  unsigned* flBmy = P.bar + (LAYER * 2 + 1) * 1024;
  unsigned* flBot = P.bar + ((1 - LAYER) * 2 + 1) * 1024;

  const bf16x8 SENT = sent8();
  f32x4 hreg = {0.f, 0.f, 0.f, 0.f};
  f32x4 zreg = {0.f, 0.f, 0.f, 0.f};

  for (int t = 0; t < SEQ; ++t) {
    f32x4 vz[4], vr[4], vg[4];
    bf16x8 s0[4], s1[4], s2[4], s3[4];

    // ===== A_pre (L0): ALL THREE x-projections — before any wait =====
    if constexpr (!LAYER) {
      const unsigned short* xB = P.xbf + (size_t)t * IN + kslX;
      #pragma unroll
      for (int mt = 0; mt < 4; ++mt) {
        const unsigned short* xp = xB + (size_t)(16 * mt + lo) * (SEQ * IN);
        bf16x8 x0 = *(const bf16x8*)(xp);
        bf16x8 x1 = *(const bf16x8*)(xp + 32);
        f32x4 a = {0,0,0,0}, b = {0,0,0,0}, c = {0,0,0,0};
        a = mfma16(x0, wxz[0], a); a = mfma16(x1, wxz[1], a);
        b = mfma16(x0, wxr[0], b); b = mfma16(x1, wxr[1], b);
        c = mfma16(x0, wxg[0], c); c = mfma16(x1, wxg[1], c);
        vz[mt] = a; vr[mt] = b; vg[mt] = c;
      }
    } else {
      #pragma unroll
      for (int mt = 0; mt < 4; ++mt) { vz[mt] = {0,0,0,0}; vr[mt] = {0,0,0,0}; vg[mt] = {0,0,0,0}; }
    }

    // lagged WAR / skew-bound (all-64, normally pre-satisfied):
    // flB >= t-1 guards rh-slot re-sentinel + bounds skew for h0/h1 staleness
    if (t >= 2) flag_poll(flBmy, (unsigned)(t - 1));

    // ===== A data (sentinel polls, per-wave) =====
    if constexpr (LAYER) {
      const unsigned short* yB = P.h0r + (size_t)(t & 7) * SLOT + kslH;
      SPOLL(yB);
      YCMP3(0, s0); YCMP3(1, s1); YCMP3(2, s2); YCMP3(3, s3);
      if (t) {
        const unsigned short* hB = P.h1r + (size_t)((t - 1) & 3) * SLOT + kslH;
        SPOLL(hB);
        GCMP2(0, s0, whz, whr); GCMP2(1, s1, whz, whr);
        GCMP2(2, s2, whz, whr); GCMP2(3, s3, whz, whr);
      }
    } else {
      if (t) {
        const unsigned short* hB = P.h0r + (size_t)((t - 1) & 7) * SLOT + kslH;
        SPOLL(hB);
        GCMP2(0, s0, whz, whr); GCMP2(1, s1, whz, whr);
        GCMP2(2, s2, whz, whr); GCMP2(3, s3, whz, whr);
      }
    }

    // reduce z,r
    f32x4 keepz, keepr;
    #pragma unroll
    for (int mt = 0; mt < 4; ++mt) {
      if (w == mt) { keepz = vz[mt]; keepr = vr[mt]; }
      else {
        int col = (w > mt) ? (w - 1) : w;
        red[mt][col][lane] = vz[mt];
        red[4 + mt][col][lane] = vr[mt];
      }
    }
    __syncthreads();
    if (w < 4) {
      f32x4 sz = keepz, sr = keepr;
      #pragma unroll
      for (int j = 0; j < 7; ++j) { sz += red[w][j][lane]; sr += red[4 + w][j][lane]; }
      unsigned short* tl = (unsigned short*)&red[4 + w][0][0];
      #pragma unroll
      for (int q = 0; q < 4; ++q) {
        float z = sigmoidf_(sz[q] + bz);
        float r = sigmoidf_(sr[q] + br);
        zreg[q] = z;
        tl[(4 * hi + q) * 24 + lo] = f2bf(r * hreg[q]);
      }
      asm volatile("s_waitcnt lgkmcnt(0)" ::: "memory");
      __builtin_amdgcn_sched_barrier(0);
      if (lane < 32) {
        const int r8 = lane >> 1, s8 = (lane & 1) * 8;
        const size_t off = (size_t)(16 * w + r8) * HD + wgl * 16 + s8;
        bf16x8 v = *(const bf16x8*)(tl + r8 * 24 + s8);
        stc16(RHr + (size_t)(t & 3) * SLOT + off, v);
        stc16(RHr + (size_t)((t + 2) & 3) * SLOT + off, SENT);   // re-sentinel future slot
      }
    }
    asm volatile("s_waitcnt vmcnt(0)" ::: "memory");
    __syncthreads();
    flag_set(flAmy, wgl, (unsigned)(t + 1));

    // ===== B: lagged WAR (h parity/ring + skew bound) =====
    if (t) flag_poll(flAmy, (unsigned)t);
    if constexpr (!LAYER) {
      if (t >= 4) flag_poll(flBot, (unsigned)(t - 3));  // h0 ring WAR vs L1 readers
    }

    // ===== B data: rh(t) sentinel poll (slot always written by A(t)) =====
    {
      const unsigned short* rB = RHr + (size_t)(t & 3) * SLOT + kslH;
      SPOLL(rB);
      RCMP1(0, s0); RCMP1(1, s1); RCMP1(2, s2); RCMP1(3, s3);
    }
    f32x4 keepg;
    #pragma unroll
    for (int mt = 0; mt < 4; ++mt) {
      if (w == mt) keepg = vg[mt];
      else { int col = (w > mt) ? (w - 1) : w; red[mt][col][lane] = vg[mt]; }
    }
    __syncthreads();
    if (w < 4) {
      f32x4 sg = keepg;
      #pragma unroll
      for (int j = 0; j < 7; ++j) sg += red[w][j][lane];
      unsigned short* tl = (unsigned short*)&red[4 + w][0][0];
      #pragma unroll
      for (int q = 0; q < 4; ++q) {
        const int row = 16 * w + 4 * hi + q;
        float g = tanhf(sg[q] + bg);
        float hn = zreg[q] * hreg[q] + (1.f - zreg[q]) * g;
        hreg[q] = hn;
        tl[(4 * hi + q) * 24 + lo] = f2bf(hn);
        if (t == SEQ - 1) P.outh[(size_t)row * (2 * HD) + LAYER * HD + cC] = hn;
      }
      asm volatile("s_waitcnt lgkmcnt(0)" ::: "memory");
      __builtin_amdgcn_sched_barrier(0);
      if (lane < 32) {
        const int r8 = lane >> 1, s8 = (lane & 1) * 8;
        const size_t off = (size_t)(16 * w + r8) * HD + wgl * 16 + s8;
        bf16x8 v = *(const bf16x8*)(tl + r8 * 24 + s8);
        if constexpr (LAYER) {
          stc16(P.h1r + (size_t)(t & 3) * SLOT + off, v);
          stc16(P.h1r + (size_t)((t + 2) & 3) * SLOT + off, SENT);
          unsigned short* yp = P.y1 + ((size_t)(16 * w + r8) * SEQ + t) * HD + wgl * 16 + s8;
          *(bf16x8*)yp = v;   // plain cached store (read by out_gemm after kernel end)
        } else {
          stc16(P.h0r + (size_t)(t & 7) * SLOT + off, v);
          stc16(P.h0r + (size_t)((t + 4) & 7) * SLOT + off, SENT);
        }
      }
    }
    asm volatile("s_waitcnt vmcnt(0)" ::: "memory");
    __syncthreads();
    flag_set(flBmy, wgl, (unsigned)(t + 1));
  }
}

__global__ __launch_bounds__(WGTH, 1) void gru_persist(GruP P) {
  __shared__ f32x4 red[8][7][64];
  if (blockIdx.x < 64) gru_body<0>(P, red);
  else gru_body<1>(P, red);
}

// C[M=B*SEQ][ODIM] = Y[M][HD] @ Wp(packed)[ODIM][HD]^T + bias
__global__ __launch_bounds__(256) void out_gemm(const unsigned short* __restrict__ Y,
                                                const unsigned short* __restrict__ Wp,
                                                const float* __restrict__ bias,
                                                float* __restrict__ C) {
  const int w = threadIdx.x >> 6, lane = threadIdx.x & 63;
  const int lo = lane & 15, hi = lane >> 4;
  const int row0 = blockIdx.x * 64;
  const int col0 = blockIdx.y * 64 + w * 16;
  const unsigned short* wp = Wp + ((size_t)(col0 >> 4) * (HD >> 5)) * 512 + (size_t)lane * 8;
  const unsigned short* yp = Y + (size_t)(row0 + lo) * HD + hi * 8;
  f32x4 a0 = {0,0,0,0}, a1 = {0,0,0,0}, a2 = {0,0,0,0}, a3 = {0,0,0,0};
  #pragma unroll 4
  for (int kb = 0; kb < (HD >> 5); ++kb) {
    bf16x8 bw = *(const bf16x8*)(wp + kb * 512);
    const int k = kb * 32;
    a0 = mfma16(*(const bf16x8*)(yp + k), bw, a0);
    a1 = mfma16(*(const bf16x8*)(yp + (size_t)16 * HD + k), bw, a1);
    a2 = mfma16(*(const bf16x8*)(yp + (size_t)32 * HD + k), bw, a2);
    a3 = mfma16(*(const bf16x8*)(yp + (size_t)48 * HD + k), bw, a3);
  }
  const int cc = col0 + lo;
  const float bb = bias[cc];
  const int rbase = row0 + 4 * hi;
  #pragma unroll
  for (int q = 0; q < 4; ++q) {
    C[(size_t)(rbase + q) * ODIM + cc]      = a0[q] + bb;
    C[(size_t)(rbase + 16 + q) * ODIM + cc] = a1[q] + bb;
    C[(size_t)(rbase + 32 + q) * ODIM + cc] = a2[q] + bb;
    C[(size_t)(rbase + 48 + q) * ODIM + cc] = a3[q] + bb;
  }
}

extern "C" void kernel_launch(void* const* d_in, const int* in_sizes, int n_in,
                              void* d_out, int out_size, void* d_ws, size_t ws_size,
                              hipStream_t stream) {
  char* ws = (char*)d_ws;
  size_t off = 0;
  auto take = [&](size_t bytes) -> char* {
    char* p = ws + off;
    off += (bytes + 255) & ~(size_t)255;
    return p;
  };

  unsigned short* xbf = (unsigned short*)take((size_t)B * SEQ * IN * 2);
  unsigned short *wx0[3], *wh0[3], *wx1[3], *wh1[3];
  for (int g = 0; g < 3; ++g) wx0[g] = (unsigned short*)take((size_t)HD * IN * 2);
  for (int g = 0; g < 3; ++g) wh0[g] = (unsigned short*)take((size_t)HD * HD * 2);
  for (int g = 0; g < 3; ++g) wx1[g] = (unsigned short*)take((size_t)HD * HD * 2);
  for (int g = 0; g < 3; ++g) wh1[g] = (unsigned short*)take((size_t)HD * HD * 2);
  unsigned short* whyb = (unsigned short*)take((size_t)ODIM * HD * 2);
  unsigned short* y1 = (unsigned short*)take((size_t)B * SEQ * HD * 2);
  const size_t SLOTB = (size_t)B * HD * 2;
  // rings: h0(8) + h1(4) + rh0(4) + rh1(4) = 20 slots, contiguous for fill
  unsigned short* rings = (unsigned short*)take(20 * SLOTB);
  unsigned short* h0r  = rings;
  unsigned short* h1r  = rings + 8 * (SLOTB / 2);
  unsigned short* rh0r = rings + 12 * (SLOTB / 2);
  unsigned short* rh1r = rings + 16 * (SLOTB / 2);
  unsigned* bar = (unsigned*)take((size_t)4 * 4096);

  {
    int n = B * SEQ * IN;
    hipLaunchKernelGGL(f32_to_bf16_k, dim3((n / 4 + 255) / 256), dim3(256), 0, stream,
                       (const float*)d_in[0], xbf, n);
  }

  {
    PackP pp;
    int s = 0;
    pp.seg[s++] = { (const float*)d_in[1],  wx0[0], HD, IN };
    pp.seg[s++] = { (const float*)d_in[4],  wx0[1], HD, IN };
    pp.seg[s++] = { (const float*)d_in[7],  wx0[2], HD, IN };
    pp.seg[s++] = { (const float*)d_in[3],  wh0[0], HD, HD };
    pp.seg[s++] = { (const float*)d_in[6],  wh0[1], HD, HD };
    pp.seg[s++] = { (const float*)d_in[9],  wh0[2], HD, HD };
    pp.seg[s++] = { (const float*)d_in[10], wx1[0], HD, HD };
    pp.seg[s++] = { (const float*)d_in[13], wx1[1], HD, HD };
    pp.seg[s++] = { (const float*)d_in[16], wx1[2], HD, HD };
    pp.seg[s++] = { (const float*)d_in[12], wh1[0], HD, HD };
    pp.seg[s++] = { (const float*)d_in[15], wh1[1], HD, HD };
    pp.seg[s++] = { (const float*)d_in[18], wh1[2], HD, HD };
    pp.seg[s++] = { (const float*)d_in[19], whyb, ODIM, HD };
    hipLaunchKernelGGL(pack_w, dim3(512, 13), dim3(256), 0, stream, pp);
  }

  // sentinel-fill rings + zero flags (every launch)
  hipLaunchKernelGGL(fill_sent, dim3(2048), dim3(256), 0, stream,
                     (unsigned*)rings, 20 * SLOTB / 4);
  hipMemsetAsync(bar, 0, (size_t)4 * 4096, stream);

  GruP P;
  P.xbf = xbf;
  for (int g = 0; g < 3; ++g) {
    P.wx[0][g] = wx0[g]; P.wh[0][g] = wh0[g];
    P.wx[1][g] = wx1[g]; P.wh[1][g] = wh1[g];
  }
  P.bx[0][0] = (const float*)d_in[2];  P.bx[0][1] = (const float*)d_in[5];  P.bx[0][2] = (const float*)d_in[8];
  P.bx[1][0] = (const float*)d_in[11]; P.bx[1][1] = (const float*)d_in[14]; P.bx[1][2] = (const float*)d_in[17];
  P.h0r = h0r;
  P.h1r = h1r;
  P.rhr[0] = rh0r;
  P.rhr[1] = rh1r;
  P.y1 = y1;
  P.outh = (float*)d_out + (size_t)B * SEQ * ODIM;
  P.bar = bar;

  hipLaunchKernelGGL(gru_persist, dim3(128), dim3(WGTH), 0, stream, P);

  hipLaunchKernelGGL(out_gemm, dim3((B * SEQ) / 64, ODIM / 64), dim3(256), 0, stream,
                     (const unsigned short*)y1, (const unsigned short*)whyb,
                     (const float*)d_in[20], (float*)d_out);
}

// Round 16
// 4157.273 us; speedup vs baseline: 1.5425x; 1.5425x over previous
//
#include <hip/hip_runtime.h>
#include <hip/hip_bf16.h>

#define B 64
#define SEQ 256
#define IN 512
#define HD 1024
#define ODIM 512
#define WGTH 512

typedef __attribute__((ext_vector_type(8))) short bf16x8;
typedef __attribute__((ext_vector_type(4))) float f32x4;
typedef __attribute__((ext_vector_type(4))) unsigned short u16x4;

__device__ __forceinline__ f32x4 mfma16(bf16x8 a, bf16x8 b, f32x4 c) {
  return __builtin_amdgcn_mfma_f32_16x16x32_bf16(a, b, c, 0, 0, 0);
}

__device__ __forceinline__ unsigned short f2bf(float f) {
  unsigned u = __builtin_bit_cast(unsigned, f);
  u += 0x7FFFu + ((u >> 16) & 1u);
  return (unsigned short)(u >> 16);
}

__device__ __forceinline__ float sigmoidf_(float x) { return 1.f / (1.f + expf(-x)); }

// coalesced 16B write-through store (LLC-coherent cross-XCD) — R12 proven
__device__ __forceinline__ void stc16(unsigned short* p, bf16x8 v) {
  asm volatile("global_store_dwordx4 %0, %1, off sc1" : : "v"(p), "v"(v) : "memory");
}

// coherent 16B load: bypass L1+L2, read LLC. No waitcnt — caller manages vmcnt.
__device__ __forceinline__ void ldg16(bf16x8& d, const unsigned short* p) {
  asm volatile("global_load_dwordx4 %0, %1, off sc0 sc1" : "=v"(d) : "v"(p) : "memory");
}

template <int N>
__device__ __forceinline__ void vmwait() {
  asm volatile("s_waitcnt vmcnt(%0)" :: "i"(N) : "memory");
  __builtin_amdgcn_sched_barrier(0);
}

// ---------------- distributed-flag barrier ----------------
__device__ __forceinline__ void flag_set(unsigned* fl, int wgl, unsigned val) {
  if (threadIdx.x == 0) {
    unsigned* p = fl + wgl * 16;
    asm volatile("s_waitcnt vmcnt(0)\n\t"
                 "global_store_dword %0, %1, off sc0 sc1"
                 :: "v"(p), "v"(val) : "memory");
  }
}

// all-64 poll (lagged WAR checks only — pre-satisfied under bounded skew)
__device__ __forceinline__ void flag_poll(const unsigned* fl, unsigned tgt) {
  if (threadIdx.x < 64) {
    const unsigned* p = fl + threadIdx.x * 16;
    for (;;) {
      unsigned v;
      asm volatile("global_load_dword %0, %1, off sc0 sc1\n\t"
                   "s_waitcnt vmcnt(0)" : "=v"(v) : "v"(p) : "memory");
      if (__ballot(v < tgt) == 0ull) break;
      __builtin_amdgcn_s_sleep(2);
    }
  }
  __syncthreads();
}

// per-wave poll of THIS WAVE's 8 producers (no block barrier)
__device__ __forceinline__ void wpoll1(const unsigned* fl, int w, unsigned tgt) {
  const int lane = threadIdx.x & 63;
  const unsigned* p = fl + (size_t)((w << 3) + (lane & 7)) * 16;
  for (;;) {
    unsigned v = tgt;
    if (lane < 8)
      asm volatile("global_load_dword %0, %1, off sc0 sc1\n\t"
                   "s_waitcnt vmcnt(0)" : "=v"(v) : "v"(p) : "memory");
    if (__ballot(v < tgt) == 0ull) break;
    __builtin_amdgcn_s_sleep(1);
  }
}

__device__ __forceinline__ void wpoll2w(const unsigned* f1, unsigned t1,
                                        const unsigned* f2, unsigned t2, int w) {
  const int lane = threadIdx.x & 63;
  const unsigned* p1 = f1 + (size_t)((w << 3) + (lane & 7)) * 16;
  const unsigned* p2 = f2 + (size_t)((w << 3) + (lane & 7)) * 16;
  for (;;) {
    unsigned v1 = t1, v2 = t2;
    if (lane < 8)
      asm volatile("global_load_dword %0, %2, off sc0 sc1\n\t"
                   "global_load_dword %1, %3, off sc0 sc1\n\t"
                   "s_waitcnt vmcnt(0)"
                   : "=v"(v1), "=v"(v2) : "v"(p1), "v"(p2) : "memory");
    if ((__ballot(v1 < t1) | __ballot(v2 < t2)) == 0ull) break;
    __builtin_amdgcn_s_sleep(1);
  }
}

// ---- x: f32 -> bf16 ----
__global__ void f32_to_bf16_k(const float* __restrict__ s, unsigned short* __restrict__ d, int n) {
  int i = (blockIdx.x * blockDim.x + threadIdx.x) * 4;
  if (i < n) {
    float4 v = *reinterpret_cast<const float4*>(s + i);
    u16x4 o;
    o.x = f2bf(v.x); o.y = f2bf(v.y); o.z = f2bf(v.z); o.w = f2bf(v.w);
    *reinterpret_cast<u16x4*>(d + i) = o;
  }
}

// ---- weights: f32 [N][K] -> bf16 packed MFMA B-fragment layout ----
struct PackSeg { const float* s; unsigned short* d; int N; int K; };
struct PackP { PackSeg seg[13]; };

__global__ void pack_w(PackP P) {
  PackSeg sg = P.seg[blockIdx.y];
  const int kc_n = sg.K >> 5;
  const int total = (sg.N * sg.K) >> 3;
  for (int i = blockIdx.x * blockDim.x + threadIdx.x; i < total; i += gridDim.x * blockDim.x) {
    int lane = i & 63;
    int block = i >> 6;
    int kc = block % kc_n;
    int nt = block / kc_n;
    int n = nt * 16 + (lane & 15);
    int k = kc * 32 + (lane >> 4) * 8;
    const float* s = sg.s + (size_t)n * sg.K + k;
    float4 v0 = *(const float4*)(s);
    float4 v1 = *(const float4*)(s + 4);
    u16x4 o0, o1;
    o0.x = f2bf(v0.x); o0.y = f2bf(v0.y); o0.z = f2bf(v0.z); o0.w = f2bf(v0.w);
    o1.x = f2bf(v1.x); o1.y = f2bf(v1.y); o1.z = f2bf(v1.z); o1.w = f2bf(v1.w);
    unsigned short* dp = sg.d + (size_t)i * 8;
    *(u16x4*)(dp) = o0;
    *(u16x4*)(dp + 4) = o1;
  }
}

struct GruP {
  const unsigned short* xbf;
  const unsigned short* wx[2][3];
  const unsigned short* wh[2][3];
  const float* bx[2][3];
  unsigned short* h0b[8];    // layer0 h ring (depth 8)
  unsigned short* h1b[4];    // layer1 h ring (depth 4)
  unsigned short* rh[2][4];  // [layer][slot] ring depth 4
  unsigned short* y1;
  float* outh;
  unsigned* bar;             // 4 flag regions x 4KB (L0A,L0B,L1A,L1B)
};

#define GISS(mt, sArr, baseP) do { \
    const unsigned short* _p = (baseP) + (size_t)(16 * (mt) + lo) * HD; \
    ldg16(sArr[0], _p);      ldg16(sArr[1], _p + 32); \
    ldg16(sArr[2], _p + 64); ldg16(sArr[3], _p + 96); \
  } while (0)

#define GCMP2(mt, sArr, wz_, wr_) do { \
    f32x4 _a = vz[mt], _b = vr[mt]; \
    _a = mfma16(sArr[0], wz_[0], _a); _b = mfma16(sArr[0], wr_[0], _b); \
    _a = mfma16(sArr[1], wz_[1], _a); _b = mfma16(sArr[1], wr_[1], _b); \
    _a = mfma16(sArr[2], wz_[2], _a); _b = mfma16(sArr[2], wr_[2], _b); \
    _a = mfma16(sArr[3], wz_[3], _a); _b = mfma16(sArr[3], wr_[3], _b); \
    vz[mt] = _a; vr[mt] = _b; \
  } while (0)

// all three gates from y (L1, CX==4)
#define YCMP3(mt, s) do { \
    f32x4 _z = vz[mt], _r = vr[mt], _g = vg[mt]; \
    _z = mfma16(s[0], wxz[0], _z); _r = mfma16(s[0], wxr[0], _r); _g = mfma16(s[0], wxg[0], _g); \
    _z = mfma16(s[1], wxz[1], _z); _r = mfma16(s[1], wxr[1], _r); _g = mfma16(s[1], wxg[1], _g); \
    _z = mfma16(s[2], wxz[2], _z); _r = mfma16(s[2], wxr[2], _r); _g = mfma16(s[2], wxg[2], _g); \
    _z = mfma16(s[3], wxz[3], _z); _r = mfma16(s[3], wxr[3], _r); _g = mfma16(s[3], wxg[3], _g); \
    vz[mt] = _z; vr[mt] = _r; vg[mt] = _g; \
  } while (0)

#define RCMP1(mt, s) do { \
    f32x4 _a = vg[mt]; \
    _a = mfma16(s[0], whg[0], _a); _a = mfma16(s[1], whg[1], _a); \
    _a = mfma16(s[2], whg[2], _a); _a = mfma16(s[3], whg[3], _a); \
    vg[mt] = _a; \
  } while (0)

template <int LAYER>
__device__ void gru_body(const GruP& P, f32x4 (*red)[7][64]) {
  const int wgl = (int)blockIdx.x & 63;
  const int tid = threadIdx.x;
  const int w = tid >> 6;            // 8 waves: k-slice owner; waves 0-3 own m-tile w
  const int lane = tid & 63;
  const int lo = lane & 15, hi = lane >> 4;
  const int cC = wgl * 16 + lo;
  constexpr int KX = LAYER ? HD : IN;
  constexpr int CX = KX / 256;       // L0:2, L1:4
  constexpr int CH = 4;
  const int kslH = w * 128 + hi * 8;
  const int kslX = w * (KX >> 3) + hi * 8;

  // register-resident weights (packed frag layout, ntile = wgl)
  bf16x8 whz[CH], whr[CH], whg[CH], wxz[CX], wxr[CX], wxg[CX];
  #pragma unroll
  for (int c = 0; c < CH; ++c) {
    size_t o = ((size_t)wgl * (HD / 32) + w * CH + c) * 512 + (size_t)lane * 8;
    whz[c] = *(const bf16x8*)(P.wh[LAYER][0] + o);
    whr[c] = *(const bf16x8*)(P.wh[LAYER][1] + o);
    whg[c] = *(const bf16x8*)(P.wh[LAYER][2] + o);
  }
  #pragma unroll
  for (int c = 0; c < CX; ++c) {
    size_t o = ((size_t)wgl * (KX / 32) + w * CX + c) * 512 + (size_t)lane * 8;
    wxz[c] = *(const bf16x8*)(P.wx[LAYER][0] + o);
    wxr[c] = *(const bf16x8*)(P.wx[LAYER][1] + o);
    wxg[c] = *(const bf16x8*)(P.wx[LAYER][2] + o);
  }
  const float bz = P.bx[LAYER][0][cC];
  const float br = P.bx[LAYER][1][cC];
  const float bg = P.bx[LAYER][2][cC];

  unsigned* flAmy = P.bar + (LAYER * 2 + 0) * 1024;
  unsigned* flBmy = P.bar + (LAYER * 2 + 1) * 1024;
  unsigned* flBot = P.bar + ((1 - LAYER) * 2 + 1) * 1024;

  f32x4 hreg = {0.f, 0.f, 0.f, 0.f};
  f32x4 zreg = {0.f, 0.f, 0.f, 0.f};

  for (int t = 0; t < SEQ; ++t) {
    f32x4 vz[4], vr[4], vg[4];
    bf16x8 sS0[4], sS1[4];
    unsigned short* RHcur = P.rh[LAYER][t & 3];

    // ===== A_pre (L0): ALL THREE x-projections — before any wait =====
    if constexpr (!LAYER) {
      const unsigned short* xB = P.xbf + (size_t)t * IN + kslX;
      #pragma unroll
      for (int mt = 0; mt < 4; ++mt) {
        const unsigned short* xp = xB + (size_t)(16 * mt + lo) * (SEQ * IN);
        bf16x8 x0 = *(const bf16x8*)(xp);
        bf16x8 x1 = *(const bf16x8*)(xp + 32);
        f32x4 a = {0,0,0,0}, b = {0,0,0,0}, c = {0,0,0,0};
        a = mfma16(x0, wxz[0], a); a = mfma16(x1, wxz[1], a);
        b = mfma16(x0, wxr[0], b); b = mfma16(x1, wxr[1], b);
        c = mfma16(x0, wxg[0], c); c = mfma16(x1, wxg[1], c);
        vz[mt] = a; vr[mt] = b; vg[mt] = c;
      }
      // lagged WAR (all-64, ring-4): B(t-4) done -> rh slot t&3 free
      if (t >= 4) flag_poll(flBmy, (unsigned)(t - 3));
      // data dep (per-wave, 8 producers): h0(t-1) slice ready
      if (t) wpoll1(flBmy, w, (unsigned)t);
    } else {
      if (t >= 4) flag_poll(flBmy, (unsigned)(t - 3));          // lagged rh WAR
      if (t) wpoll2w(flBot, (unsigned)(t + 1), flBmy, (unsigned)t, w);  // y(t) + h1(t-1)
      else   wpoll1(flBot, w, (unsigned)(t + 1));
    }

    // ===== A_post =====
    if constexpr (LAYER) {
      const unsigned short* yB = P.h0b[t & 7] + kslH;   // y0(t), stride HD
      #pragma unroll
      for (int mt = 0; mt < 4; ++mt) { vz[mt] = {0,0,0,0}; vr[mt] = {0,0,0,0}; vg[mt] = {0,0,0,0}; }
      GISS(0, sS0, yB); GISS(1, sS1, yB);
      vmwait<4>(); YCMP3(0, sS0); GISS(2, sS0, yB);
      vmwait<4>(); YCMP3(1, sS1); GISS(3, sS1, yB);
      vmwait<4>(); YCMP3(2, sS0);
      vmwait<0>(); YCMP3(3, sS1);
    }
    {
      const unsigned short* hB = (LAYER ? P.h1b[(t + 3) & 3] : P.h0b[(t + 7) & 7]) + kslH;
      GISS(0, sS0, hB); GISS(1, sS1, hB);
      vmwait<4>(); GCMP2(0, sS0, whz, whr); GISS(2, sS0, hB);
      vmwait<4>(); GCMP2(1, sS1, whz, whr); GISS(3, sS1, hB);
      vmwait<4>(); GCMP2(2, sS0, whz, whr);
      vmwait<0>(); GCMP2(3, sS1, whz, whr);
    }
    // reduce z,r
    f32x4 keepz, keepr;
    #pragma unroll
    for (int mt = 0; mt < 4; ++mt) {
      if (w == mt) { keepz = vz[mt]; keepr = vr[mt]; }
      else {
        int col = (w > mt) ? (w - 1) : w;
        red[mt][col][lane] = vz[mt];
        red[4 + mt][col][lane] = vr[mt];
      }
    }
    __syncthreads();
    if (w < 4) {
      f32x4 sz = keepz, sr = keepr;
      #pragma unroll
      for (int j = 0; j < 7; ++j) { sz += red[w][j][lane]; sr += red[4 + w][j][lane]; }
      unsigned short* tl = (unsigned short*)&red[4 + w][0][0];
      #pragma unroll
      for (int q = 0; q < 4; ++q) {
        float z = sigmoidf_(sz[q] + bz);
        float r = sigmoidf_(sr[q] + br);
        zreg[q] = z;
        tl[(4 * hi + q) * 24 + lo] = f2bf(r * hreg[q]);
      }
      asm volatile("s_waitcnt lgkmcnt(0)" ::: "memory");
      __builtin_amdgcn_sched_barrier(0);
      if (lane < 32) {
        const int r8 = lane >> 1, s8 = (lane & 1) * 8;
        bf16x8 v = *(const bf16x8*)(tl + r8 * 24 + s8);
        stc16(RHcur + (size_t)(16 * w + r8) * HD + wgl * 16 + s8, v);
      }
    }
    asm volatile("s_waitcnt vmcnt(0)" ::: "memory");
    __syncthreads();
    flag_set(flAmy, wgl, (unsigned)(t + 1));

    // ===== wait B =====
    // lagged WAR (all-64, ring-4): A(t-3) done -> h slot t&3 (h1) / subset for h0 ring-8
    if (t >= 3) flag_poll(flAmy, (unsigned)(t - 2));
    if constexpr (!LAYER) {
      if (t >= 8) flag_poll(flBot, (unsigned)(t - 7));  // h0 ring-8 WAR vs L1 readers
    }
    wpoll1(flAmy, w, (unsigned)(t + 1));                // data dep: rh(t) slice, 8 producers

    // ===== B_post: (r.h) @ Whg + h update (vg carried from phase A) =====
    {
      const unsigned short* rB = RHcur + kslH;
      GISS(0, sS0, rB); GISS(1, sS1, rB);
      vmwait<4>(); RCMP1(0, sS0); GISS(2, sS0, rB);
      vmwait<4>(); RCMP1(1, sS1); GISS(3, sS1, rB);
      vmwait<4>(); RCMP1(2, sS0);
      vmwait<0>(); RCMP1(3, sS1);
    }
    f32x4 keepg;
    #pragma unroll
    for (int mt = 0; mt < 4; ++mt) {
      if (w == mt) keepg = vg[mt];
      else { int col = (w > mt) ? (w - 1) : w; red[mt][col][lane] = vg[mt]; }
    }
    __syncthreads();
    if (w < 4) {
      f32x4 sg = keepg;
      #pragma unroll
      for (int j = 0; j < 7; ++j) sg += red[w][j][lane];
      unsigned short* hW = LAYER ? P.h1b[t & 3] : P.h0b[t & 7];
      unsigned short* tl = (unsigned short*)&red[4 + w][0][0];
      #pragma unroll
      for (int q = 0; q < 4; ++q) {
        const int row = 16 * w + 4 * hi + q;
        float g = tanhf(sg[q] + bg);
        float hn = zreg[q] * hreg[q] + (1.f - zreg[q]) * g;
        hreg[q] = hn;
        tl[(4 * hi + q) * 24 + lo] = f2bf(hn);
        if (t == SEQ - 1) P.outh[(size_t)row * (2 * HD) + LAYER * HD + cC] = hn;
      }
      asm volatile("s_waitcnt lgkmcnt(0)" ::: "memory");
      __builtin_amdgcn_sched_barrier(0);
      if (lane < 32) {
        const int r8 = lane >> 1, s8 = (lane & 1) * 8;
        bf16x8 v = *(const bf16x8*)(tl + r8 * 24 + s8);
        stc16(hW + (size_t)(16 * w + r8) * HD + wgl * 16 + s8, v);
        if (LAYER) {
          unsigned short* yp = P.y1 + ((size_t)(16 * w + r8) * SEQ + t) * HD + wgl * 16 + s8;
          *(bf16x8*)yp = v;   // plain cached store (read by out_gemm after kernel end)
        }
      }
    }
    asm volatile("s_waitcnt vmcnt(0)" ::: "memory");
    __syncthreads();
    flag_set(flBmy, wgl, (unsigned)(t + 1));
  }
}

__global__ __launch_bounds__(WGTH, 1) void gru_persist(GruP P) {
  __shared__ f32x4 red[8][7][64];
  if (blockIdx.x < 64) gru_body<0>(P, red);
  else gru_body<1>(P, red);
}

// C[M=B*SEQ][ODIM] = Y[M][HD] @ Wp(packed)[ODIM][HD]^T + bias
__global__ __launch_bounds__(256) void out_gemm(const unsigned short* __restrict__ Y,
                                                const unsigned short* __restrict__ Wp,
                                                const float* __restrict__ bias,
                                                float* __restrict__ C) {
  const int w = threadIdx.x >> 6, lane = threadIdx.x & 63;
  const int lo = lane & 15, hi = lane >> 4;
  const int row0 = blockIdx.x * 64;
  const int col0 = blockIdx.y * 64 + w * 16;
  const unsigned short* wp = Wp + ((size_t)(col0 >> 4) * (HD >> 5)) * 512 + (size_t)lane * 8;
  const unsigned short* yp = Y + (size_t)(row0 + lo) * HD + hi * 8;
  f32x4 a0 = {0,0,0,0}, a1 = {0,0,0,0}, a2 = {0,0,0,0}, a3 = {0,0,0,0};
  #pragma unroll 4
  for (int kb = 0; kb < (HD >> 5); ++kb) {
    bf16x8 bw = *(const bf16x8*)(wp + kb * 512);
    const int k = kb * 32;
    a0 = mfma16(*(const bf16x8*)(yp + k), bw, a0);
    a1 = mfma16(*(const bf16x8*)(yp + (size_t)16 * HD + k), bw, a1);
    a2 = mfma16(*(const bf16x8*)(yp + (size_t)32 * HD + k), bw, a2);
    a3 = mfma16(*(const bf16x8*)(yp + (size_t)48 * HD + k), bw, a3);
  }
  const int cc = col0 + lo;
  const float bb = bias[cc];
  const int rbase = row0 + 4 * hi;
  #pragma unroll
  for (int q = 0; q < 4; ++q) {
    C[(size_t)(rbase + q) * ODIM + cc]      = a0[q] + bb;
    C[(size_t)(rbase + 16 + q) * ODIM + cc] = a1[q] + bb;
    C[(size_t)(rbase + 32 + q) * ODIM + cc] = a2[q] + bb;
    C[(size_t)(rbase + 48 + q) * ODIM + cc] = a3[q] + bb;
  }
}

extern "C" void kernel_launch(void* const* d_in, const int* in_sizes, int n_in,
                              void* d_out, int out_size, void* d_ws, size_t ws_size,
                              hipStream_t stream) {
  char* ws = (char*)d_ws;
  size_t off = 0;
  auto take = [&](size_t bytes) -> char* {
    char* p = ws + off;
    off += (bytes + 255) & ~(size_t)255;
    return p;
  };

  unsigned short* xbf = (unsigned short*)take((size_t)B * SEQ * IN * 2);
  unsigned short *wx0[3], *wh0[3], *wx1[3], *wh1[3];
  for (int g = 0; g < 3; ++g) wx0[g] = (unsigned short*)take((size_t)HD * IN * 2);
  for (int g = 0; g < 3; ++g) wh0[g] = (unsigned short*)take((size_t)HD * HD * 2);
  for (int g = 0; g < 3; ++g) wx1[g] = (unsigned short*)take((size_t)HD * HD * 2);
  for (int g = 0; g < 3; ++g) wh1[g] = (unsigned short*)take((size_t)HD * HD * 2);
  unsigned short* whyb = (unsigned short*)take((size_t)ODIM * HD * 2);
  unsigned short* y1 = (unsigned short*)take((size_t)B * SEQ * HD * 2);
  char* state0 = ws + off;
  unsigned short* h0r[8];
  for (int i = 0; i < 8; ++i) h0r[i] = (unsigned short*)take((size_t)B * HD * 2);
  unsigned short* h1p[4];
  for (int i = 0; i < 4; ++i) h1p[i] = (unsigned short*)take((size_t)B * HD * 2);
  unsigned short* rhp[2][4];
  for (int l = 0; l < 2; ++l)
    for (int i = 0; i < 4; ++i) rhp[l][i] = (unsigned short*)take((size_t)B * HD * 2);
  unsigned* bar = (unsigned*)take((size_t)4 * 4096);
  size_t stateBytes = (size_t)((ws + off) - state0);

  {
    int n = B * SEQ * IN;
    hipLaunchKernelGGL(f32_to_bf16_k, dim3((n / 4 + 255) / 256), dim3(256), 0, stream,
                       (const float*)d_in[0], xbf, n);
  }

  {
    PackP pp;
    int s = 0;
    pp.seg[s++] = { (const float*)d_in[1],  wx0[0], HD, IN };
    pp.seg[s++] = { (const float*)d_in[4],  wx0[1], HD, IN };
    pp.seg[s++] = { (const float*)d_in[7],  wx0[2], HD, IN };
    pp.seg[s++] = { (const float*)d_in[3],  wh0[0], HD, HD };
    pp.seg[s++] = { (const float*)d_in[6],  wh0[1], HD, HD };
    pp.seg[s++] = { (const float*)d_in[9],  wh0[2], HD, HD };
    pp.seg[s++] = { (const float*)d_in[10], wx1[0], HD, HD };
    pp.seg[s++] = { (const float*)d_in[13], wx1[1], HD, HD };
    pp.seg[s++] = { (const float*)d_in[16], wx1[2], HD, HD };
    pp.seg[s++] = { (const float*)d_in[12], wh1[0], HD, HD };
    pp.seg[s++] = { (const float*)d_in[15], wh1[1], HD, HD };
    pp.seg[s++] = { (const float*)d_in[18], wh1[2], HD, HD };
    pp.seg[s++] = { (const float*)d_in[19], whyb, ODIM, HD };
    hipLaunchKernelGGL(pack_w, dim3(512, 13), dim3(256), 0, stream, pp);
  }

  hipMemsetAsync(state0, 0, stateBytes, stream);

  GruP P;
  P.xbf = xbf;
  for (int g = 0; g < 3; ++g) {
    P.wx[0][g] = wx0[g]; P.wh[0][g] = wh0[g];
    P.wx[1][g] = wx1[g]; P.wh[1][g] = wh1[g];
  }
  P.bx[0][0] = (const float*)d_in[2];  P.bx[0][1] = (const float*)d_in[5];  P.bx[0][2] = (const float*)d_in[8];
  P.bx[1][0] = (const float*)d_in[11]; P.bx[1][1] = (const float*)d_in[14]; P.bx[1][2] = (const float*)d_in[17];
  for (int i = 0; i < 8; ++i) P.h0b[i] = h0r[i];
  for (int i = 0; i < 4; ++i) P.h1b[i] = h1p[i];
  for (int l = 0; l < 2; ++l)
    for (int i = 0; i < 4; ++i) P.rh[l][i] = rhp[l][i];
  P.y1 = y1;
  P.outh = (float*)d_out + (size_t)B * SEQ * ODIM;
  P.bar = bar;

  hipLaunchKernelGGL(gru_persist, dim3(128), dim3(WGTH), 0, stream, P);

  hipLaunchKernelGGL(out_gemm, dim3((B * SEQ) / 64, ODIM / 64), dim3(256), 0, stream,
                     (const unsigned short*)y1, (const unsigned short*)whyb,
                     (const float*)d_in[20], (float*)d_out);
}